// Round 5
// baseline (319.239 us; speedup 1.0000x reference)
//
#include <hip/hip_runtime.h>
#include <hip/hip_bf16.h>
#include <math.h>

#define HIDDEN 256
#define INV_SCALE 0.17677669529663687f  /* 1/sqrt(32) */

typedef __attribute__((ext_vector_type(8))) short short8;
typedef __attribute__((ext_vector_type(4))) float f32x4;
typedef const __attribute__((address_space(1))) unsigned int* gas_ptr;
typedef __attribute__((address_space(3))) unsigned int* las_ptr;

static __device__ __forceinline__ unsigned short f2bf(float x) {
  unsigned u = __float_as_uint(x);
  unsigned r = (u + 0x7FFF + ((u >> 16) & 1)) >> 16;
  return (unsigned short)r;
}
static __device__ __forceinline__ float bf2f(unsigned short u) {
  return __uint_as_float((unsigned)u << 16);
}

#define GLL(gp, lp) __builtin_amdgcn_global_load_lds((gas_ptr)(const void*)(gp), (las_ptr)(void*)(lp), 16, 0, 0)

// ---------------- input / weight conversion to bf16 ----------------

__global__ __launch_bounds__(256) void conv_a_kernel(const float* __restrict__ in,
                                                     unsigned short* __restrict__ out,
                                                     int total4) {
  int stride = gridDim.x * blockDim.x;
  for (int i = blockIdx.x * blockDim.x + threadIdx.x; i < total4; i += stride) {
    float4 f = ((const float4*)in)[i];
    ushort4 u;
    u.x = f2bf(f.x); u.y = f2bf(f.y); u.z = f2bf(f.z); u.w = f2bf(f.w);
    ((ushort4*)out)[i] = u;
  }
}

// Wq,Wk,Wv -> wqkv[768][256], Wo -> wob[256][256]
__global__ __launch_bounds__(256) void conv_w_kernel(const float* __restrict__ Wq,
                                                     const float* __restrict__ Wk,
                                                     const float* __restrict__ Wv,
                                                     const float* __restrict__ Wo,
                                                     unsigned short* __restrict__ wqkv,
                                                     unsigned short* __restrict__ wob) {
  int i = blockIdx.x * 256 + threadIdx.x;  // grid 1024 -> 262144
  int m = i >> 16;
  int j = i & 65535;
  const float* s = (m == 0) ? Wq : (m == 1) ? Wk : (m == 2) ? Wv : Wo;
  unsigned short b = f2bf(s[j]);
  if (m < 3) wqkv[m * 65536 + j] = b;
  else wob[j] = b;
}

// ---------------- CSR build ----------------

__global__ __launch_bounds__(256) void hist_kernel(const int* __restrict__ dst,
                                                   int* __restrict__ deg, int E) {
  int e = blockIdx.x * blockDim.x + threadIdx.x;
  if (e < E) atomicAdd(&deg[dst[e]], 1);
}

__global__ __launch_bounds__(256) void scan1_kernel(const int* __restrict__ deg,
                                                    int* __restrict__ offs,
                                                    int* __restrict__ bsums, int N) {
  __shared__ int s[256];
  int tid = threadIdx.x;
  int base = blockIdx.x * 1024 + tid * 4;
  int v0 = (base + 0 < N) ? deg[base + 0] : 0;
  int v1 = (base + 1 < N) ? deg[base + 1] : 0;
  int v2 = (base + 2 < N) ? deg[base + 2] : 0;
  int v3 = (base + 3 < N) ? deg[base + 3] : 0;
  int tsum = v0 + v1 + v2 + v3;
  s[tid] = tsum;
  __syncthreads();
  for (int off = 1; off < 256; off <<= 1) {
    int t = (tid >= off) ? s[tid - off] : 0;
    __syncthreads();
    s[tid] += t;
    __syncthreads();
  }
  int excl = s[tid] - tsum;
  if (base + 0 < N) offs[base + 0] = excl;
  if (base + 1 < N) offs[base + 1] = excl + v0;
  if (base + 2 < N) offs[base + 2] = excl + v0 + v1;
  if (base + 3 < N) offs[base + 3] = excl + v0 + v1 + v2;
  if (tid == 255) bsums[blockIdx.x] = s[255];
}

__global__ void scan2_kernel(int* __restrict__ bsums, int nb) {
  if (blockIdx.x == 0 && threadIdx.x == 0) {
    int run = 0;
    for (int b = 0; b < nb; ++b) { int t = bsums[b]; bsums[b] = run; run += t; }
  }
}

__global__ __launch_bounds__(256) void scan3_kernel(int* __restrict__ offs,
                                                    int* __restrict__ cursor,
                                                    const int* __restrict__ bsums,
                                                    int N, int E) {
  int i = blockIdx.x * blockDim.x + threadIdx.x;
  if (i < N) {
    int v = offs[i] + bsums[i >> 10];
    offs[i] = v;
    cursor[i] = v;
  }
  if (i == 0) offs[N] = E;
}

__global__ __launch_bounds__(256) void scatter_kernel(const int* __restrict__ dst,
                                                      const int* __restrict__ src,
                                                      int* __restrict__ cursor,
                                                      int* __restrict__ esrc, int E) {
  int e = blockIdx.x * blockDim.x + threadIdx.x;
  if (e < E) {
    int n = dst[e];
    int pos = atomicAdd(&cursor[n], 1);
    esrc[pos] = src[e];
  }
}

// ---------------- bf16 MFMA GEMM, 2-phase pipelined, 128x256 tile ----------------
// MODE 0: fused QKV (Ncols=768): cols 0-255 -> q bf16 (+bias), 256-511 -> k bf16, 512-767 -> v bf16
// MODE 1: out projection (Ncols=256): fp32 + bias
#define GBM 128
#define GBN 256
#define GBK 32
#define NKSTEP (HIDDEN / GBK)

template <int MODE>
__global__ __launch_bounds__(256, 2) void mfma_gemm_kernel(const unsigned short* __restrict__ A,
                                                           const unsigned short* __restrict__ B,
                                                           const float* __restrict__ bias,
                                                           float* __restrict__ Cf,
                                                           unsigned short* __restrict__ Cq,
                                                           unsigned short* __restrict__ Ck,
                                                           unsigned short* __restrict__ Cv,
                                                           int M) {
  __shared__ unsigned short As[2][GBM][GBK];  // 16 KB
  __shared__ unsigned short Bs[2][GBN][GBK];  // 32 KB
  int tid = threadIdx.x;
  int lane = tid & 63;
  int wid = tid >> 6;
  int wm = wid >> 1, wn = wid & 1;   // wave tile: 64 rows x 128 cols
  int brow = blockIdx.x * GBM;
  int bcol = blockIdx.y * GBN;

  // staging: wave wid covers A rows [wid*32,+32) (2 chunks), B rows [wid*64,+64) (4 chunks)
  int srow = lane >> 2;          // 0..15
  int skoff = (lane & 3) * 8;    // elements
  const unsigned short* gA = &A[(size_t)(brow + wid * 32 + srow) * HIDDEN + skoff];
  const unsigned short* gB = &B[(size_t)(bcol + wid * 64 + srow) * HIDDEN + skoff];
  char* ldsA = (char*)&As[0][0][0] + wid * 2048;
  char* ldsB = (char*)&Bs[0][0][0] + wid * 4096;

  f32x4 acc[4][8] = {};
  int fr = lane & 15;
  int kg = (lane >> 4) * 8;

  // prologue: stage tile 0 into buffer 0
  GLL(gA, ldsA); GLL(gA + 16 * HIDDEN, ldsA + 1024);
  GLL(gB, ldsB); GLL(gB + 16 * HIDDEN, ldsB + 1024);
  GLL(gB + 32 * HIDDEN, ldsB + 2048); GLL(gB + 48 * HIDDEN, ldsB + 3072);

#pragma unroll
  for (int t = 0; t < NKSTEP; ++t) {
    int p = t & 1;
    if (t + 1 < NKSTEP) {
      int k1 = (t + 1) * GBK;
      char* dA = ldsA + ((t + 1) & 1) * 8192;
      char* dB = ldsB + ((t + 1) & 1) * 16384;
      GLL(gA + k1, dA); GLL(gA + k1 + 16 * HIDDEN, dA + 1024);
      GLL(gB + k1, dB); GLL(gB + k1 + 16 * HIDDEN, dB + 1024);
      GLL(gB + k1 + 32 * HIDDEN, dB + 2048); GLL(gB + k1 + 48 * HIDDEN, dB + 3072);
      asm volatile("s_waitcnt vmcnt(6)" ::: "memory");  // tile t's 6 loads done
    } else {
      asm volatile("s_waitcnt vmcnt(0)" ::: "memory");
    }
    __builtin_amdgcn_s_barrier();
    __builtin_amdgcn_sched_barrier(0);
    short8 af[4], bfg[8];
#pragma unroll
    for (int mi = 0; mi < 4; ++mi)
      af[mi] = *(const short8*)&As[p][wm * 64 + mi * 16 + fr][kg];
#pragma unroll
    for (int ni = 0; ni < 8; ++ni)
      bfg[ni] = *(const short8*)&Bs[p][wn * 128 + ni * 16 + fr][kg];
#pragma unroll
    for (int mi = 0; mi < 4; ++mi)
#pragma unroll
      for (int ni = 0; ni < 8; ++ni)
        acc[mi][ni] = __builtin_amdgcn_mfma_f32_16x16x32_bf16(af[mi], bfg[ni], acc[mi][ni], 0, 0, 0);
    __builtin_amdgcn_s_barrier();  // all waves done reading buf p before restage
  }

  int fq = lane >> 4;
#pragma unroll
  for (int mi = 0; mi < 4; ++mi) {
#pragma unroll
    for (int ni = 0; ni < 8; ++ni) {
      int c = bcol + wn * 128 + ni * 16 + fr;
#pragma unroll
      for (int j = 0; j < 4; ++j) {
        int r = brow + wm * 64 + mi * 16 + fq * 4 + j;
        if (r < M) {
          float val = acc[mi][ni][j];
          if (MODE == 1) {
            Cf[(size_t)r * HIDDEN + c] = val + bias[c];
          } else {
            if (c < 256) Cq[(size_t)r * HIDDEN + c] = f2bf(val + bias[c]);
            else if (c < 512) Ck[(size_t)r * HIDDEN + (c - 256)] = f2bf(val);
            else Cv[(size_t)r * HIDDEN + (c - 512)] = f2bf(val);
          }
        }
      }
    }
  }
}

// ---------------- per-dst-node attention aggregation ----------------
// 1 wave per node, 4 quarter-waves process 4 edges concurrently.
// lane = 16*qd + l; lane owns channels [l*16, l*16+16); head = l>>1 (pair reduce).
__global__ __launch_bounds__(256) void agg_kernel(const unsigned short* __restrict__ q,
                                                  const unsigned short* __restrict__ k,
                                                  const unsigned short* __restrict__ v,
                                                  const int* __restrict__ offs,
                                                  const int* __restrict__ esrc,
                                                  unsigned short* __restrict__ o, int N) {
  int n = blockIdx.x * 4 + (threadIdx.x >> 6);
  if (n >= N) return;
  int lane = threadIdx.x & 63;
  int qd = lane >> 4;   // quarter 0..3
  int l = lane & 15;    // owns ch [l*16, l*16+16)

  float qf[16];
  {
    const short8* qp = (const short8*)&q[(size_t)n * HIDDEN + l * 16];
    short8 q0 = qp[0], q1 = qp[1];
#pragma unroll
    for (int j = 0; j < 8; ++j) {
      qf[j] = bf2f((unsigned short)q0[j]);
      qf[8 + j] = bf2f((unsigned short)q1[j]);
    }
  }

  int e0 = offs[n], e1 = offs[n + 1];
  float wv[16] = {};
  float z = 0.f;

  for (int idx = e0; idx < e1; idx += 4) {
    int my = idx + qd;
    bool valid = my < e1;
    int s = esrc[valid ? my : (e1 - 1)];
    const short8* kp = (const short8*)&k[(size_t)s * HIDDEN + l * 16];
    const short8* vp = (const short8*)&v[(size_t)s * HIDDEN + l * 16];
    short8 k0 = kp[0], k1 = kp[1];
    short8 v0 = vp[0], v1 = vp[1];
    float d0 = 0.f, d1 = 0.f;
#pragma unroll
    for (int j = 0; j < 8; ++j) {
      d0 += qf[j] * bf2f((unsigned short)k0[j]);
      d1 += qf[8 + j] * bf2f((unsigned short)k1[j]);
    }
    float dot = d0 + d1;
    dot += __shfl_xor(dot, 1);  // lane pair = one 32-ch head
    float e = valid ? __expf(fminf(fmaxf(dot * INV_SCALE, -10.f), 10.f)) : 0.f;
#pragma unroll
    for (int j = 0; j < 8; ++j) {
      wv[j] += e * bf2f((unsigned short)v0[j]);
      wv[8 + j] += e * bf2f((unsigned short)v1[j]);
    }
    z += e;
  }

  // combine the four quarters
#pragma unroll
  for (int j = 0; j < 16; ++j) {
    wv[j] += __shfl_xor(wv[j], 16);
    wv[j] += __shfl_xor(wv[j], 32);
  }
  z += __shfl_xor(z, 16);
  z += __shfl_xor(z, 32);

  if (qd == 0) {
    float inv = 1.0f / z;
    short8 o0, o1;
#pragma unroll
    for (int j = 0; j < 8; ++j) {
      o0[j] = (short)f2bf(wv[j] * inv);
      o1[j] = (short)f2bf(wv[8 + j] * inv);
    }
    short8* op = (short8*)&o[(size_t)n * HIDDEN + l * 16];
    op[0] = o0; op[1] = o1;
  }
}

// ---------------- launch ----------------

extern "C" void kernel_launch(void* const* d_in, const int* in_sizes, int n_in,
                              void* d_out, int out_size, void* d_ws, size_t ws_size,
                              hipStream_t stream) {
  const float* inputs = (const float*)d_in[0];
  const float* Wq = (const float*)d_in[1];
  const float* bq = (const float*)d_in[2];
  const float* Wk = (const float*)d_in[3];
  const float* Wv = (const float*)d_in[4];
  const float* Wo = (const float*)d_in[5];
  const float* bo = (const float*)d_in[6];
  const int* src = (const int*)d_in[7];
  const int* dst = (const int*)d_in[8];

  int N = in_sizes[0] / HIDDEN;
  int E = in_sizes[7];
  int Mpad = N + GBM;  // pad rows so GEMM staging overrun stays in allocated ws

  char* w = (char*)d_ws;
  unsigned short* a_bf = (unsigned short*)w; w += (size_t)Mpad * HIDDEN * 2;
  unsigned short* qb = (unsigned short*)w;   w += (size_t)N * HIDDEN * 2;
  unsigned short* kb = (unsigned short*)w;   w += (size_t)N * HIDDEN * 2;
  unsigned short* vb = (unsigned short*)w;   w += (size_t)N * HIDDEN * 2;
  unsigned short* ob = (unsigned short*)w;   w += (size_t)Mpad * HIDDEN * 2;
  unsigned short* wqkv = (unsigned short*)w; w += (size_t)768 * HIDDEN * 2;
  unsigned short* wob = (unsigned short*)w;  w += (size_t)256 * HIDDEN * 2;
  int* deg = (int*)w;    w += (size_t)N * 4;
  int* offs = (int*)w;   w += (size_t)(N + 4) * 4;
  int* cursor = (int*)w; w += (size_t)N * 4;
  int* esrc = (int*)w;   w += (size_t)E * 4;
  int* bsums = (int*)w;  w += 256 * 4;

  // conversions
  conv_a_kernel<<<2048, 256, 0, stream>>>(inputs, a_bf, N * (HIDDEN / 4));
  conv_w_kernel<<<1024, 256, 0, stream>>>(Wq, Wk, Wv, Wo, wqkv, wob);

  // CSR build
  hipMemsetAsync(deg, 0, (size_t)N * 4, stream);
  int eb = (E + 255) / 256;
  hist_kernel<<<eb, 256, 0, stream>>>(dst, deg, E);
  int nb = (N + 1023) / 1024;
  scan1_kernel<<<nb, 256, 0, stream>>>(deg, offs, bsums, N);
  scan2_kernel<<<1, 64, 0, stream>>>(bsums, nb);
  scan3_kernel<<<(N + 255) / 256, 256, 0, stream>>>(offs, cursor, bsums, N, E);
  scatter_kernel<<<eb, 256, 0, stream>>>(dst, src, cursor, esrc, E);

  // fused QKV projection (bf16 MFMA)
  dim3 gqkv((N + GBM - 1) / GBM, 768 / GBN);
  mfma_gemm_kernel<0><<<gqkv, 256, 0, stream>>>(a_bf, wqkv, bq, nullptr, qb, kb, vb, N);

  // attention aggregation
  agg_kernel<<<(N + 3) / 4, 256, 0, stream>>>(qb, kb, vb, offs, esrc, ob, N);

  // output projection
  dim3 gout((N + GBM - 1) / GBM, 256 / GBN);
  mfma_gemm_kernel<1><<<gout, 256, 0, stream>>>(ob, wob, bo, (float*)d_out, nullptr, nullptr, nullptr, N);
}